// Round 1
// baseline (325.978 us; speedup 1.0000x reference)
//
#include <hip/hip_runtime.h>
#include <hip/hip_bf16.h>
#include <stdint.h>

// MultiHeadAttention: B=2, T=2048, E=1024, H=16, hd=64
// Pipeline: cvt(fp32->bf16) -> proj3 GEMM (q,k,v) -> flash attn -> out-proj GEMM

#define NHEAD 16
#define SEQT  2048
#define EDIM  1024
#define HD    64
#define MB    2
#define MTOT  (MB*SEQT)   // 4096

typedef __attribute__((ext_vector_type(4))) float f32x4;
typedef __attribute__((ext_vector_type(8))) short s16x8;

typedef const __attribute__((address_space(1))) void* GPtr;
typedef __attribute__((address_space(3))) void* LPtr;

__device__ __forceinline__ ushort f2bf(float f) {
    uint32_t u = __float_as_uint(f);
    u += 0x7FFF + ((u >> 16) & 1);   // round-to-nearest-even
    return (ushort)(u >> 16);
}
__device__ __forceinline__ float bf2f(ushort h) {
    return __uint_as_float(((uint32_t)h) << 16);
}

__device__ __forceinline__ void gload_lds16(const void* g, void* l) {
    __builtin_amdgcn_global_load_lds((GPtr)g, (LPtr)l, 16, 0, 0);
}

// ---------------- fp32 -> bf16 conversion ----------------
__global__ void cvt_kernel(const float* __restrict__ src, ushort* __restrict__ dst, int n4) {
    int idx = blockIdx.x * blockDim.x + threadIdx.x;
    int stride = gridDim.x * blockDim.x;
    for (int i = idx; i < n4; i += stride) {
        float4 v = reinterpret_cast<const float4*>(src)[i];
        ushort4 o;
        o.x = f2bf(v.x); o.y = f2bf(v.y); o.z = f2bf(v.z); o.w = f2bf(v.w);
        reinterpret_cast<ushort4*>(dst)[i] = o;
    }
}

// ---------------- GEMM body: C = A(MxK) * W(NxK)^T + bias ----------------
// m97 structure: 128x128 tile, BK=32, global_load_lds width 16, 4 waves 2x2,
// each wave 64x64 out = 4x4 MFMA 16x16x32 frags.
// OUTMODE 0: bf16 out, permuted to (B,H,T,hd).  OUTMODE 1: fp32 row-major.
template<int OUTMODE>
__device__ __forceinline__ void gemm_body(const ushort* __restrict__ A,
                                          const ushort* __restrict__ W,
                                          const float* __restrict__ bias,
                                          void* __restrict__ out)
{
    const int K = 1024, N = 1024;
    __shared__ ushort As[128 * 32];
    __shared__ ushort Bs[128 * 32];

    const int tid  = threadIdx.x;
    const int lane = tid & 63;
    const int wid  = tid >> 6;
    const int wr = wid >> 1, wc = wid & 1;
    const int bm = blockIdx.y, bn = blockIdx.x;

    f32x4 acc[4][4];
#pragma unroll
    for (int i = 0; i < 4; i++)
#pragma unroll
        for (int j = 0; j < 4; j++) acc[i][j] = (f32x4){0.f, 0.f, 0.f, 0.f};

    const ushort* Abase = A + (size_t)(bm * 128) * K;
    const ushort* Wbase = W + (size_t)(bn * 128) * K;
    // wave-uniform LDS staging bases (global_load_lds: dest = base + lane*16B)
    ushort* AsW = As + wid * 512;
    ushort* BsW = Bs + wid * 512;
    const int srow = tid >> 2;          // 0..63
    const int scol = (tid & 3) * 8;

    const int afoff = (wr * 64 + (lane & 15)) * 32 + (lane >> 4) * 8;
    const int bfoff = (wc * 64 + (lane & 15)) * 32 + (lane >> 4) * 8;

    for (int k0 = 0; k0 < K; k0 += 32) {
#pragma unroll
        for (int j = 0; j < 2; j++) {
            gload_lds16(Abase + (size_t)(j * 64 + srow) * K + k0 + scol, AsW + j * 2048);
            gload_lds16(Wbase + (size_t)(j * 64 + srow) * K + k0 + scol, BsW + j * 2048);
        }
        __syncthreads();

        s16x8 af[4], bf[4];
#pragma unroll
        for (int i = 0; i < 4; i++)
            af[i] = *reinterpret_cast<const s16x8*>(&As[afoff + i * 16 * 32]);
#pragma unroll
        for (int j = 0; j < 4; j++)
            bf[j] = *reinterpret_cast<const s16x8*>(&Bs[bfoff + j * 16 * 32]);
#pragma unroll
        for (int i = 0; i < 4; i++)
#pragma unroll
            for (int j = 0; j < 4; j++)
                acc[i][j] = __builtin_amdgcn_mfma_f32_16x16x32_bf16(af[i], bf[j], acc[i][j], 0, 0, 0);
        __syncthreads();
    }

    // epilogue: C/D layout col=lane&15, row=(lane>>4)*4+reg  [m89/m91 verified]
    const int orow0 = bm * 128 + wr * 64 + (lane >> 4) * 4;
    const int ocol0 = bn * 128 + wc * 64 + (lane & 15);
#pragma unroll
    for (int i = 0; i < 4; i++) {
#pragma unroll
        for (int j = 0; j < 4; j++) {
            int col = ocol0 + j * 16;
            float bv = bias[col];
#pragma unroll
            for (int r = 0; r < 4; r++) {
                int row = orow0 + i * 16 + r;
                float v = acc[i][j][r] + bv;
                if (OUTMODE == 0) {
                    int b = row >> 11, t = row & (SEQT - 1);
                    int h = col >> 6,  d = col & 63;
                    ((ushort*)out)[(((size_t)b * NHEAD + h) * SEQT + t) * HD + d] = f2bf(v);
                } else {
                    ((float*)out)[(size_t)row * N + col] = v;
                }
            }
        }
    }
}

__global__ __launch_bounds__(256, 2)
void proj3_kernel(const ushort* xq, const ushort* xk, const ushort* xv,
                  const ushort* wq, const ushort* wk, const ushort* wv,
                  const float* bq, const float* bk, const float* bv,
                  ushort* oq, ushort* ok, ushort* ov)
{
    int z = blockIdx.z;
    const ushort* A = (z == 0) ? xq : (z == 1) ? xk : xv;
    const ushort* W = (z == 0) ? wq : (z == 1) ? wk : wv;
    const float* bi = (z == 0) ? bq : (z == 1) ? bk : bv;
    ushort* o       = (z == 0) ? oq : (z == 1) ? ok : ov;
    gemm_body<0>(A, W, bi, o);
}

__global__ __launch_bounds__(256, 2)
void oproj_kernel(const ushort* __restrict__ A, const ushort* __restrict__ W,
                  const float* __restrict__ bias, float* __restrict__ out)
{
    gemm_body<1>(A, W, bias, out);
}

// ---------------- flash attention ----------------
// grid (T/128, B*H), 512 threads = 8 waves x 16 q-rows. KBLK=64.
#define KBLK 64
#define DPAD 72   // 64 + 8 pad: row stride 144B -> 2-way bank aliasing (free)

__global__ __launch_bounds__(512, 2)
void attn_kernel(const ushort* __restrict__ Qg, const ushort* __restrict__ Kg,
                 const ushort* __restrict__ Vg, ushort* __restrict__ Og)
{
    __shared__ ushort Ks[KBLK][DPAD];     // [key][d]
    __shared__ ushort Vts[HD][DPAD];      // [d][key] (transposed on stage)
    __shared__ ushort Ps[8][16][DPAD];    // per-wave P tile

    const int tid  = threadIdx.x;
    const int lane = tid & 63;
    const int wid  = tid >> 6;
    const int bh   = blockIdx.y;
    const int q0   = blockIdx.x * 128;

    const ushort* Qb = Qg + (size_t)bh * SEQT * HD;
    const ushort* Kb = Kg + (size_t)bh * SEQT * HD;
    const ushort* Vb = Vg + (size_t)bh * SEQT * HD;

    // Q fragments held in registers for whole kernel; fold scale = log2(e)/sqrt(hd)
    const float CS = 0.18033688011112042f;
    s16x8 qf[2];
    {
        int r  = q0 + wid * 16 + (lane & 15);
        int d0 = (lane >> 4) * 8;
#pragma unroll
        for (int kk = 0; kk < 2; kk++) {
            s16x8 raw = *reinterpret_cast<const s16x8*>(&Qb[(size_t)r * HD + kk * 32 + d0]);
            s16x8 sc;
#pragma unroll
            for (int i = 0; i < 8; i++) sc[i] = (short)f2bf(bf2f((ushort)raw[i]) * CS);
            qf[kk] = sc;
        }
    }

    f32x4 o[4];
#pragma unroll
    for (int i = 0; i < 4; i++) o[i] = (f32x4){0.f, 0.f, 0.f, 0.f};
    float mrow[4], lrow[4];
#pragma unroll
    for (int r = 0; r < 4; r++) { mrow[r] = -1e30f; lrow[r] = 0.f; }

    for (int t0 = 0; t0 < SEQT; t0 += KBLK) {
        // ---- stage K tile and transposed V tile (512 threads, 8 bf16 each) ----
        {
            int e  = tid * 8;
            int kr = e >> 6;       // key row 0..63
            int dc = e & 63;       // d col: 0,8,...,56
            s16x8 kv = *reinterpret_cast<const s16x8*>(&Kb[(size_t)(t0 + kr) * HD + dc]);
            *reinterpret_cast<s16x8*>(&Ks[kr][dc]) = kv;
            s16x8 vv = *reinterpret_cast<const s16x8*>(&Vb[(size_t)(t0 + kr) * HD + dc]);
#pragma unroll
            for (int i = 0; i < 8; i++) {          // staggered to avoid bank conflicts
                int ii = (i + tid) & 7;
                Vts[dc + ii][kr] = (ushort)vv[ii];
            }
        }
        __syncthreads();

        // ---- QK^T: S[16 q][64 key] ----
        f32x4 s[4];
#pragma unroll
        for (int nj = 0; nj < 4; nj++) {
            f32x4 a = (f32x4){0.f, 0.f, 0.f, 0.f};
#pragma unroll
            for (int kk = 0; kk < 2; kk++) {
                s16x8 kf = *reinterpret_cast<const s16x8*>(
                    &Ks[nj * 16 + (lane & 15)][kk * 32 + (lane >> 4) * 8]);
                a = __builtin_amdgcn_mfma_f32_16x16x32_bf16(qf[kk], kf, a, 0, 0, 0);
            }
            s[nj] = a;
        }

        // ---- online softmax (scores already scaled by log2e) ----
        float alpha[4], rsum[4];
#pragma unroll
        for (int r = 0; r < 4; r++) {
            float m0 = fmaxf(fmaxf(s[0][r], s[1][r]), fmaxf(s[2][r], s[3][r]));
#pragma unroll
            for (int off = 1; off < 16; off <<= 1) m0 = fmaxf(m0, __shfl_xor(m0, off));
            float mn = fmaxf(mrow[r], m0);
            alpha[r] = exp2f(mrow[r] - mn);
            mrow[r] = mn;
            rsum[r] = 0.f;
        }
        const int prow = (lane >> 4) * 4;
        const int pcol = lane & 15;
#pragma unroll
        for (int nj = 0; nj < 4; nj++) {
#pragma unroll
            for (int r = 0; r < 4; r++) {
                float p = exp2f(s[nj][r] - mrow[r]);
                rsum[r] += p;
                Ps[wid][prow + r][nj * 16 + pcol] = f2bf(p);
            }
        }
#pragma unroll
        for (int r = 0; r < 4; r++) {
            float su = rsum[r];
#pragma unroll
            for (int off = 1; off < 16; off <<= 1) su += __shfl_xor(su, off);
            lrow[r] = lrow[r] * alpha[r] + su;
        }
#pragma unroll
        for (int dj = 0; dj < 4; dj++)
#pragma unroll
            for (int r = 0; r < 4; r++) o[dj][r] *= alpha[r];

        // ---- PV: O += P(16x64) @ V(64x64) ----
        s16x8 pa[2];
#pragma unroll
        for (int kk = 0; kk < 2; kk++)
            pa[kk] = *reinterpret_cast<const s16x8*>(
                &Ps[wid][lane & 15][kk * 32 + (lane >> 4) * 8]);
#pragma unroll
        for (int dj = 0; dj < 4; dj++) {
#pragma unroll
            for (int kk = 0; kk < 2; kk++) {
                s16x8 vf = *reinterpret_cast<const s16x8*>(
                    &Vts[dj * 16 + (lane & 15)][kk * 32 + (lane >> 4) * 8]);
                o[dj] = __builtin_amdgcn_mfma_f32_16x16x32_bf16(pa[kk], vf, o[dj], 0, 0, 0);
            }
        }
        __syncthreads();
    }

    // ---- epilogue: merged-head layout (B*T, E) bf16 ----
    const int b = bh >> 4, h = bh & 15;
    const int trow = q0 + wid * 16 + (lane >> 4) * 4;
#pragma unroll
    for (int dj = 0; dj < 4; dj++) {
        int col = h * 64 + dj * 16 + (lane & 15);
#pragma unroll
        for (int r = 0; r < 4; r++) {
            float v = o[dj][r] / lrow[r];
            Og[((size_t)b * SEQT + trow + r) * EDIM + col] = f2bf(v);
        }
    }
}

// ---------------- launch ----------------
extern "C" void kernel_launch(void* const* d_in, const int* in_sizes, int n_in,
                              void* d_out, int out_size, void* d_ws, size_t ws_size,
                              hipStream_t stream)
{
    const float* query = (const float*)d_in[0];
    const float* key   = (const float*)d_in[1];
    const float* value = (const float*)d_in[2];
    const float* Wq    = (const float*)d_in[3];
    const float* Wk    = (const float*)d_in[4];
    const float* Wv    = (const float*)d_in[5];
    const float* bq    = (const float*)d_in[6];
    const float* bk    = (const float*)d_in[7];
    const float* bv    = (const float*)d_in[8];
    const float* Wo    = (const float*)d_in[9];
    const float* bo    = (const float*)d_in[10];
    float* out = (float*)d_out;

    const size_t NX = (size_t)MTOT * EDIM;   // 4M elems
    const size_t NW = (size_t)EDIM * EDIM;   // 1M elems
    ushort* ws = (ushort*)d_ws;
    ushort* xq = ws;            // bf16 copies of inputs
    ushort* xk = xq + NX;
    ushort* xv = xk + NX;
    ushort* wq = xv + NX;
    ushort* wk = wq + NW;
    ushort* wv = wk + NW;
    ushort* wo = wv + NW;
    ushort* qb = wo + NW;       // projected q/k/v in (B*H, T, hd)
    ushort* kb = qb + NX;
    ushort* vb = kb + NX;
    ushort* ao = vb + NX;       // attention out, merged (B*T, E)

    const int n4x = (int)(NX / 4), n4w = (int)(NW / 4);
    cvt_kernel<<<dim3(1024), 256, 0, stream>>>(query, xq, n4x);
    cvt_kernel<<<dim3(1024), 256, 0, stream>>>(key,   xk, n4x);
    cvt_kernel<<<dim3(1024), 256, 0, stream>>>(value, xv, n4x);
    cvt_kernel<<<dim3(512),  256, 0, stream>>>(Wq, wq, n4w);
    cvt_kernel<<<dim3(512),  256, 0, stream>>>(Wk, wk, n4w);
    cvt_kernel<<<dim3(512),  256, 0, stream>>>(Wv, wv, n4w);
    cvt_kernel<<<dim3(512),  256, 0, stream>>>(Wo, wo, n4w);

    proj3_kernel<<<dim3(8, 32, 3), 256, 0, stream>>>(xq, xk, xv, wq, wk, wv,
                                                     bq, bk, bv, qb, kb, vb);

    attn_kernel<<<dim3(SEQT / 128, MB * NHEAD), 512, 0, stream>>>(qb, kb, vb, ao);

    oproj_kernel<<<dim3(8, 32), 256, 0, stream>>>(ao, wo, bo, out);
}

// Round 2
// 298.646 us; speedup vs baseline: 1.0915x; 1.0915x over previous
//
#include <hip/hip_runtime.h>
#include <hip/hip_bf16.h>
#include <stdint.h>

// MultiHeadAttention: B=2, T=2048, E=1024, H=16, hd=64
// cvt(fp32->bf16) -> projQ/projK/projVT GEMMs -> swapped-operand flash attn -> out-proj

#define NHEAD 16
#define SEQT  2048
#define EDIM  1024
#define HD    64
#define MB    2
#define MTOT  (MB*SEQT)   // 4096

typedef __attribute__((ext_vector_type(4)))  float f32x4;
typedef __attribute__((ext_vector_type(16))) float f32x16;
typedef __attribute__((ext_vector_type(8)))  short s16x8;

typedef const __attribute__((address_space(1))) void* GPtr;
typedef __attribute__((address_space(3))) void* LPtr;

static __device__ __forceinline__ ushort f2bf(float f) {
    uint32_t u = __float_as_uint(f);
    u += 0x7FFF + ((u >> 16) & 1);   // RNE
    return (ushort)(u >> 16);
}
static __device__ __forceinline__ float bf2f(ushort h) {
    return __uint_as_float(((uint32_t)h) << 16);
}
static __device__ __forceinline__ void gload_lds16(const void* g, void* l) {
    __builtin_amdgcn_global_load_lds((GPtr)g, (LPtr)l, 16, 0, 0);
}
static __device__ __forceinline__ uint cvt_pk_bf16(float lo, float hi) {
    uint r;
    asm("v_cvt_pk_bf16_f32 %0, %1, %2" : "=v"(r) : "v"(lo), "v"(hi));
    return r;
}

// ---------------- fp32 -> bf16 conversion ----------------
__global__ void cvt_kernel(const float* __restrict__ src, ushort* __restrict__ dst, int n4) {
    int idx = blockIdx.x * blockDim.x + threadIdx.x;
    int stride = gridDim.x * blockDim.x;
    for (int i = idx; i < n4; i += stride) {
        float4 v = reinterpret_cast<const float4*>(src)[i];
        ushort4 o;
        o.x = f2bf(v.x); o.y = f2bf(v.y); o.z = f2bf(v.z); o.w = f2bf(v.w);
        reinterpret_cast<ushort4*>(dst)[i] = o;
    }
}

// ---------------- GEMM body: C = A(MxK) * W(NxK)^T + bias ----------------
// OUTMODE 0: bf16, (B,H,T,hd) plain              (Q)
// OUTMODE 1: fp32 row-major                      (out-proj)
// OUTMODE 2: bf16, (B,H,hd,T) V^T, key-swizzled  (V; row=e, col=token, bias[row])
// OUTMODE 3: bf16, (B,H,T,hd), d-swizzled        (K)
template<int OUTMODE>
__device__ __forceinline__ void gemm_body(const ushort* __restrict__ A,
                                          const ushort* __restrict__ W,
                                          const float* __restrict__ bias,
                                          void* __restrict__ out)
{
    const int K = 1024, N = 1024;
    __shared__ ushort As[128 * 32];
    __shared__ ushort Bs[128 * 32];

    const int tid  = threadIdx.x;
    const int lane = tid & 63;
    const int wid  = tid >> 6;
    const int wr = wid >> 1, wc = wid & 1;
    const int bm = blockIdx.y, bn = blockIdx.x;

    f32x4 acc[4][4];
#pragma unroll
    for (int i = 0; i < 4; i++)
#pragma unroll
        for (int j = 0; j < 4; j++) acc[i][j] = (f32x4){0.f, 0.f, 0.f, 0.f};

    const ushort* Abase = A + (size_t)(bm * 128) * K;
    const ushort* Wbase = W + (size_t)(bn * 128) * K;
    ushort* AsW = As + wid * 512;
    ushort* BsW = Bs + wid * 512;
    const int srow = tid >> 2;
    const int scol = (tid & 3) * 8;

    const int afoff = (wr * 64 + (lane & 15)) * 32 + (lane >> 4) * 8;
    const int bfoff = (wc * 64 + (lane & 15)) * 32 + (lane >> 4) * 8;

    for (int k0 = 0; k0 < K; k0 += 32) {
#pragma unroll
        for (int j = 0; j < 2; j++) {
            gload_lds16(Abase + (size_t)(j * 64 + srow) * K + k0 + scol, AsW + j * 2048);
            gload_lds16(Wbase + (size_t)(j * 64 + srow) * K + k0 + scol, BsW + j * 2048);
        }
        __syncthreads();

        s16x8 af[4], bf[4];
#pragma unroll
        for (int i = 0; i < 4; i++)
            af[i] = *reinterpret_cast<const s16x8*>(&As[afoff + i * 16 * 32]);
#pragma unroll
        for (int j = 0; j < 4; j++)
            bf[j] = *reinterpret_cast<const s16x8*>(&Bs[bfoff + j * 16 * 32]);
#pragma unroll
        for (int i = 0; i < 4; i++)
#pragma unroll
            for (int j = 0; j < 4; j++)
                acc[i][j] = __builtin_amdgcn_mfma_f32_16x16x32_bf16(af[i], bf[j], acc[i][j], 0, 0, 0);
        __syncthreads();
    }

    const int orow0 = bm * 128 + wr * 64 + (lane >> 4) * 4;
    const int ocol0 = bn * 128 + wc * 64 + (lane & 15);
#pragma unroll
    for (int i = 0; i < 4; i++) {
#pragma unroll
        for (int j = 0; j < 4; j++) {
            int col = ocol0 + j * 16;
#pragma unroll
            for (int r = 0; r < 4; r++) {
                int row = orow0 + i * 16 + r;
                float bv = (OUTMODE == 2) ? bias[row] : bias[col];
                float v = acc[i][j][r] + bv;
                if (OUTMODE == 0) {
                    int b = row >> 11, t = row & (SEQT - 1);
                    int h = col >> 6,  d = col & 63;
                    ((ushort*)out)[(((size_t)b * NHEAD + h) * SEQT + t) * HD + d] = f2bf(v);
                } else if (OUTMODE == 1) {
                    ((float*)out)[(size_t)row * N + col] = v;
                } else if (OUTMODE == 2) {
                    int h = row >> 6, d = row & 63;
                    int b = col >> 11, t = col & (SEQT - 1);
                    int tsw = (t & ~63) | ((t & 63) ^ ((d & 7) << 3));
                    ((ushort*)out)[(((size_t)b * NHEAD + h) * HD + d) * SEQT + tsw] = f2bf(v);
                } else {
                    int b = row >> 11, t = row & (SEQT - 1);
                    int h = col >> 6,  d = col & 63;
                    int dsw = d ^ ((t & 7) << 3);
                    ((ushort*)out)[(((size_t)b * NHEAD + h) * SEQT + t) * HD + dsw] = f2bf(v);
                }
            }
        }
    }
}

__global__ __launch_bounds__(256, 2)
void projQ_kernel(const ushort* A, const ushort* W, const float* bi, ushort* o) {
    gemm_body<0>(A, W, bi, o);
}
__global__ __launch_bounds__(256, 2)
void projK_kernel(const ushort* A, const ushort* W, const float* bi, ushort* o) {
    gemm_body<3>(A, W, bi, o);
}
__global__ __launch_bounds__(256, 2)
void projVT_kernel(const ushort* A, const ushort* W, const float* bi, ushort* o) {
    gemm_body<2>(A, W, bi, o);   // A = Wv, W = x  ->  C = Wv * x^T = V^T
}
__global__ __launch_bounds__(256, 2)
void oproj_kernel(const ushort* __restrict__ A, const ushort* __restrict__ W,
                  const float* __restrict__ bias, float* __restrict__ out) {
    gemm_body<1>(A, W, bias, out);
}

// ---------------- flash attention (swapped-operand, 32x32 MFMA) ----------------
// grid (T/128, B*H), 256 threads = 4 waves x 32 q-rows. KBLK=64.
// S^T = K*Q^T  (lane owns q = lane&31; keys split lane <-> lane^32)
// O^T = V^T*P^T (lane owns its q's output column -> scalar alpha/l rescale)
#define KBLK 64
#define NT (SEQT / KBLK)

__global__ __launch_bounds__(256)
void attn_kernel(const ushort* __restrict__ Qg, const ushort* __restrict__ Kg,
                 const ushort* __restrict__ Vtg, ushort* __restrict__ Og)
{
    __shared__ ushort Ks[2][KBLK * HD];   // [key][d ^ 8*(key&7)]
    __shared__ ushort Vs[2][HD * KBLK];   // [d][key ^ 8*(d&7)]

    const int tid  = threadIdx.x;
    const int lane = tid & 63;
    const int wid  = tid >> 6;
    const int g    = lane >> 5;
    const int qc   = lane & 31;
    const int bh   = blockIdx.y;
    const int q0   = blockIdx.x * 128 + wid * 32;

    const ushort* Kp = Kg  + (size_t)bh * SEQT * HD;
    const ushort* Vp = Vtg + (size_t)bh * HD * SEQT;

    // Q B-fragments in registers, prescaled by log2(e)/sqrt(hd)
    const float CS = 0.18033688011112042f;
    s16x8 qf[4];
    {
        const ushort* Qp = Qg + ((size_t)bh * SEQT + q0 + qc) * HD;
#pragma unroll
        for (int kst = 0; kst < 4; kst++) {
            s16x8 raw = *reinterpret_cast<const s16x8*>(Qp + kst * 16 + g * 8);
            s16x8 sc;
#pragma unroll
            for (int j = 0; j < 8; j++) sc[j] = (short)f2bf(bf2f((ushort)raw[j]) * CS);
            qf[kst] = sc;
        }
    }

    f32x16 oa[2];
#pragma unroll
    for (int mt = 0; mt < 2; mt++)
#pragma unroll
        for (int r = 0; r < 16; r++) oa[mt][r] = 0.f;
    float mrow = -1e30f, lrow = 0.f;

    // stage tile t0 into buffer buf (linear copy; swizzle pre-applied in global)
#define STAGE(buf, t0)                                                               \
    do {                                                                             \
        _Pragma("unroll")                                                            \
        for (int c = 0; c < 2; c++) {                                                \
            int i = c * 256 + tid;                                                   \
            gload_lds16(Kp + (size_t)((t0) + (i >> 3)) * HD + (i & 7) * 8,           \
                        &Ks[buf][(c * 256 + wid * 64) * 8]);                         \
            gload_lds16(Vp + (size_t)(i >> 3) * SEQT + (t0) + (i & 7) * 8,           \
                        &Vs[buf][(c * 256 + wid * 64) * 8]);                         \
        }                                                                            \
    } while (0)

    STAGE(0, 0);
    __syncthreads();
    int cur = 0;

    for (int t = 0; t < NT; t++) {
        if (t + 1 < NT) STAGE(cur ^ 1, (t + 1) * KBLK);
        const ushort* Kb = Ks[cur];
        const ushort* Vb = Vs[cur];

        // ---- S^T = K * Q^T : 2 m-tiles (32 keys) x 4 k-steps (16 d) ----
        f32x16 sa[2];
#pragma unroll
        for (int mt = 0; mt < 2; mt++) {
            f32x16 a;
#pragma unroll
            for (int r = 0; r < 16; r++) a[r] = 0.f;
            const int key = mt * 32 + qc;
#pragma unroll
            for (int kst = 0; kst < 4; kst++) {
                int dsw = (kst * 16 + g * 8) ^ ((key & 7) << 3);
                s16x8 kf = *reinterpret_cast<const s16x8*>(Kb + key * HD + dsw);
                a = __builtin_amdgcn_mfma_f32_32x32x16_bf16(kf, qf[kst], a, 0, 0, 0);
            }
            sa[mt] = a;
        }

        // ---- online softmax: lane owns q = qc; partner lane^32 holds other keys ----
        float mx = sa[0][0];
#pragma unroll
        for (int r = 1; r < 16; r++) mx = fmaxf(mx, sa[0][r]);
#pragma unroll
        for (int r = 0; r < 16; r++) mx = fmaxf(mx, sa[1][r]);
        mx = fmaxf(mx, __shfl_xor(mx, 32));
        float mn = fmaxf(mrow, mx);
        float alpha = exp2f(mrow - mn);
        mrow = mn;
        float rs = 0.f;
#pragma unroll
        for (int mt = 0; mt < 2; mt++)
#pragma unroll
            for (int r = 0; r < 16; r++) {
                float p = exp2f(sa[mt][r] - mn);
                sa[mt][r] = p;
                rs += p;
            }
        rs += __shfl_xor(rs, 32);
        lrow = lrow * alpha + rs;
#pragma unroll
        for (int mt = 0; mt < 2; mt++)
#pragma unroll
            for (int r = 0; r < 16; r++) oa[mt][r] *= alpha;

        // ---- pack P to bf16 pairs: pk[acc][pair] = keys {(2p&3)+8(p>>1)+4g, +1} ----
        uint pk[2][8];
#pragma unroll
        for (int aa = 0; aa < 2; aa++)
#pragma unroll
            for (int p = 0; p < 8; p++)
                pk[aa][p] = cvt_pk_bf16(sa[aa][2 * p], sa[aa][2 * p + 1]);

        // ---- O^T += V^T * P^T : per k-step assemble P^T B-frag (keys kst*16+8g+j) ----
#pragma unroll
        for (int kst = 0; kst < 4; kst++) {
            const int aa = kst >> 1;
            const int b4 = (kst & 1) * 4;
            // exchange complementary key-pairs with partner lane (lane^32)
            uint s0 = g ? pk[aa][b4 + 0] : pk[aa][b4 + 2];
            uint s1 = g ? pk[aa][b4 + 1] : pk[aa][b4 + 3];
            uint r0 = __shfl_xor(s0, 32);
            uint r1 = __shfl_xor(s1, 32);
            union { uint u[4]; s16x8 v; } pf;
            pf.u[0] = g ? r0 : pk[aa][b4 + 0];
            pf.u[1] = g ? r1 : pk[aa][b4 + 1];
            pf.u[2] = g ? pk[aa][b4 + 2] : r0;
            pf.u[3] = g ? pk[aa][b4 + 3] : r1;
#pragma unroll
            for (int mt = 0; mt < 2; mt++) {
                const int d = mt * 32 + qc;
                int ksw = (kst * 16 + g * 8) ^ ((d & 7) << 3);
                s16x8 vf = *reinterpret_cast<const s16x8*>(Vb + d * KBLK + ksw);
                oa[mt] = __builtin_amdgcn_mfma_f32_32x32x16_bf16(vf, pf.v, oa[mt], 0, 0, 0);
            }
        }
        __syncthreads();
        cur ^= 1;
    }

    // ---- epilogue: O^T -> per-wave LDS bounce -> coalesced bf16 stores ----
    float inv = 1.0f / lrow;
    ushort* Ob = &Ks[0][0] + wid * 2048;   // 4KB per wave, reuse K buffers
#pragma unroll
    for (int mt = 0; mt < 2; mt++)
#pragma unroll
        for (int p = 0; p < 8; p++) {
            int d = mt * 32 + ((2 * p) & 3) + 8 * (p >> 1) + 4 * g;
            uint v = cvt_pk_bf16(oa[mt][2 * p] * inv, oa[mt][2 * p + 1] * inv);
            *reinterpret_cast<uint*>(Ob + qc * HD + (d ^ ((qc & 7) << 3))) = v;
        }
    __syncthreads();
    const int b = bh >> 4, h = bh & 15;
    const int qr = lane >> 1, dh = (lane & 1) * 32;
    ushort* dst = Og + ((size_t)b * SEQT + q0 + qr) * EDIM + h * HD + dh;
    const ushort* src = Ob + qr * HD;
#pragma unroll
    for (int c = 0; c < 4; c++) {
        int d0 = (dh + c * 8) ^ ((qr & 7) << 3);
        *reinterpret_cast<s16x8*>(dst + c * 8) = *reinterpret_cast<const s16x8*>(src + d0);
    }
}

// ---------------- launch ----------------
extern "C" void kernel_launch(void* const* d_in, const int* in_sizes, int n_in,
                              void* d_out, int out_size, void* d_ws, size_t ws_size,
                              hipStream_t stream)
{
    const float* query = (const float*)d_in[0];
    const float* key   = (const float*)d_in[1];
    const float* value = (const float*)d_in[2];
    const float* Wq    = (const float*)d_in[3];
    const float* Wk    = (const float*)d_in[4];
    const float* Wv    = (const float*)d_in[5];
    const float* bq    = (const float*)d_in[6];
    const float* bk    = (const float*)d_in[7];
    const float* bv    = (const float*)d_in[8];
    const float* Wo    = (const float*)d_in[9];
    const float* bo    = (const float*)d_in[10];
    float* out = (float*)d_out;

    const size_t NX = (size_t)MTOT * EDIM;
    const size_t NW = (size_t)EDIM * EDIM;
    ushort* ws = (ushort*)d_ws;
    ushort* xq  = ws;
    ushort* xk  = xq + NX;
    ushort* xv  = xk + NX;
    ushort* wq  = xv + NX;
    ushort* wk  = wq + NW;
    ushort* wv  = wk + NW;
    ushort* wo  = wv + NW;
    ushort* qb  = wo + NW;   // (B,H,T,hd)
    ushort* kb  = qb + NX;   // (B,H,T,hd) d-swizzled
    ushort* vtb = kb + NX;   // (B,H,hd,T) key-swizzled
    ushort* ao  = vtb + NX;  // (B*T, E)

    const int n4x = (int)(NX / 4), n4w = (int)(NW / 4);
    cvt_kernel<<<dim3(1024), 256, 0, stream>>>(query, xq, n4x);
    cvt_kernel<<<dim3(1024), 256, 0, stream>>>(key,   xk, n4x);
    cvt_kernel<<<dim3(1024), 256, 0, stream>>>(value, xv, n4x);
    cvt_kernel<<<dim3(512),  256, 0, stream>>>(Wq, wq, n4w);
    cvt_kernel<<<dim3(512),  256, 0, stream>>>(Wk, wk, n4w);
    cvt_kernel<<<dim3(512),  256, 0, stream>>>(Wv, wv, n4w);
    cvt_kernel<<<dim3(512),  256, 0, stream>>>(Wo, wo, n4w);

    projQ_kernel <<<dim3(8, 32),  256, 0, stream>>>(xq, wq, bq, qb);
    projK_kernel <<<dim3(8, 32),  256, 0, stream>>>(xk, wk, bk, kb);
    projVT_kernel<<<dim3(32, 8),  256, 0, stream>>>(wv, xv, bv, vtb);

    attn_kernel<<<dim3(SEQT / 128, MB * NHEAD), 256, 0, stream>>>(qb, kb, vtb, ao);

    oproj_kernel<<<dim3(8, 32), 256, 0, stream>>>(ao, wo, bo, out);
}

// Round 7
// 269.000 us; speedup vs baseline: 1.2118x; 1.1102x over previous
//
#include <hip/hip_runtime.h>
#include <hip/hip_bf16.h>
#include <stdint.h>

// MultiHeadAttention: B=2, T=2048, E=1024, H=16, hd=64
// cvt(fp32->bf16, z-fused) -> proj3 (z-fused Q/K/VT GEMMs) -> flash attn
// (swapped-operand 32x32, 3-buf deep prefetch, counted vmcnt) -> out-proj

#define NHEAD 16
#define SEQT  2048
#define EDIM  1024
#define HD    64
#define MB    2
#define MTOT  (MB*SEQT)   // 4096

typedef __attribute__((ext_vector_type(4)))  float f32x4;
typedef __attribute__((ext_vector_type(16))) float f32x16;
typedef __attribute__((ext_vector_type(8)))  short s16x8;

typedef const __attribute__((address_space(1))) void* GPtr;
typedef __attribute__((address_space(3))) void* LPtr;

static __device__ __forceinline__ ushort f2bf(float f) {
    uint32_t u = __float_as_uint(f);
    u += 0x7FFF + ((u >> 16) & 1);   // RNE
    return (ushort)(u >> 16);
}
static __device__ __forceinline__ float bf2f(ushort h) {
    return __uint_as_float(((uint32_t)h) << 16);
}
static __device__ __forceinline__ void gload_lds16(const void* g, void* l) {
    __builtin_amdgcn_global_load_lds((GPtr)g, (LPtr)l, 16, 0, 0);
}
static __device__ __forceinline__ uint cvt_pk_bf16(float lo, float hi) {
    uint r;
    asm("v_cvt_pk_bf16_f32 %0, %1, %2" : "=v"(r) : "v"(lo), "v"(hi));
    return r;
}

// ---------------- fp32 -> bf16 conversion (one launch, z selects array) ----
#define N4X ((MTOT * EDIM) / 4)
#define N4W ((EDIM * EDIM) / 4)

__global__ void cvt_batch(const float* q, const float* k, const float* v,
                          const float* Wq, const float* Wk, const float* Wv,
                          const float* Wo,
                          ushort* xq, ushort* xk, ushort* xv,
                          ushort* wq, ushort* wk, ushort* wv, ushort* wo)
{
    int z = blockIdx.z;
    const float* s; ushort* d; int n4;
    if      (z == 0) { s = q;  d = xq; n4 = N4X; }
    else if (z == 1) { s = k;  d = xk; n4 = N4X; }
    else if (z == 2) { s = v;  d = xv; n4 = N4X; }
    else if (z == 3) { s = Wq; d = wq; n4 = N4W; }
    else if (z == 4) { s = Wk; d = wk; n4 = N4W; }
    else if (z == 5) { s = Wv; d = wv; n4 = N4W; }
    else             { s = Wo; d = wo; n4 = N4W; }
    int idx = blockIdx.x * blockDim.x + threadIdx.x;
    int stride = gridDim.x * blockDim.x;
    for (int i = idx; i < n4; i += stride) {
        float4 vv = reinterpret_cast<const float4*>(s)[i];
        ushort4 o;
        o.x = f2bf(vv.x); o.y = f2bf(vv.y); o.z = f2bf(vv.z); o.w = f2bf(vv.w);
        reinterpret_cast<ushort4*>(d)[i] = o;
    }
}

// ---------------- GEMM body: C = A(MxK) * W(NxK)^T + bias ----------------
// OUTMODE 0: bf16, (B,H,T,hd) plain              (Q)
// OUTMODE 1: fp32 row-major                      (out-proj)
// OUTMODE 2: bf16, (B,H,hd,T) V^T, key-swizzled  (V; row=e, col=token, bias[row])
// OUTMODE 3: bf16, (B,H,T,hd), d-swizzled        (K)
template<int OUTMODE>
__device__ __forceinline__ void gemm_body(const ushort* __restrict__ A,
                                          const ushort* __restrict__ W,
                                          const float* __restrict__ bias,
                                          void* __restrict__ out,
                                          int bm, int bn)
{
    const int K = 1024, N = 1024;
    __shared__ ushort As[128 * 32];
    __shared__ ushort Bs[128 * 32];

    const int tid  = threadIdx.x;
    const int lane = tid & 63;
    const int wid  = tid >> 6;
    const int wr = wid >> 1, wc = wid & 1;

    f32x4 acc[4][4];
#pragma unroll
    for (int i = 0; i < 4; i++)
#pragma unroll
        for (int j = 0; j < 4; j++) acc[i][j] = (f32x4){0.f, 0.f, 0.f, 0.f};

    const ushort* Abase = A + (size_t)(bm * 128) * K;
    const ushort* Wbase = W + (size_t)(bn * 128) * K;
    ushort* AsW = As + wid * 512;
    ushort* BsW = Bs + wid * 512;
    const int srow = tid >> 2;
    const int scol = (tid & 3) * 8;

    const int afoff = (wr * 64 + (lane & 15)) * 32 + (lane >> 4) * 8;
    const int bfoff = (wc * 64 + (lane & 15)) * 32 + (lane >> 4) * 8;

    for (int k0 = 0; k0 < K; k0 += 32) {
#pragma unroll
        for (int j = 0; j < 2; j++) {
            gload_lds16(Abase + (size_t)(j * 64 + srow) * K + k0 + scol, AsW + j * 2048);
            gload_lds16(Wbase + (size_t)(j * 64 + srow) * K + k0 + scol, BsW + j * 2048);
        }
        __syncthreads();

        s16x8 af[4], bf[4];
#pragma unroll
        for (int i = 0; i < 4; i++)
            af[i] = *reinterpret_cast<const s16x8*>(&As[afoff + i * 16 * 32]);
#pragma unroll
        for (int j = 0; j < 4; j++)
            bf[j] = *reinterpret_cast<const s16x8*>(&Bs[bfoff + j * 16 * 32]);
#pragma unroll
        for (int i = 0; i < 4; i++)
#pragma unroll
            for (int j = 0; j < 4; j++)
                acc[i][j] = __builtin_amdgcn_mfma_f32_16x16x32_bf16(af[i], bf[j], acc[i][j], 0, 0, 0);
        __syncthreads();
    }

    const int orow0 = bm * 128 + wr * 64 + (lane >> 4) * 4;
    const int ocol0 = bn * 128 + wc * 64 + (lane & 15);
#pragma unroll
    for (int i = 0; i < 4; i++) {
#pragma unroll
        for (int j = 0; j < 4; j++) {
            int col = ocol0 + j * 16;
#pragma unroll
            for (int r = 0; r < 4; r++) {
                int row = orow0 + i * 16 + r;
                float bv = (OUTMODE == 2) ? bias[row] : bias[col];
                float v = acc[i][j][r] + bv;
                if (OUTMODE == 0) {
                    int b = row >> 11, t = row & (SEQT - 1);
                    int h = col >> 6,  d = col & 63;
                    ((ushort*)out)[(((size_t)b * NHEAD + h) * SEQT + t) * HD + d] = f2bf(v);
                } else if (OUTMODE == 1) {
                    ((float*)out)[(size_t)row * N + col] = v;
                } else if (OUTMODE == 2) {
                    int h = row >> 6, d = row & 63;
                    int b = col >> 11, t = col & (SEQT - 1);
                    int tsw = (t & ~63) | ((t & 63) ^ ((d & 7) << 3));
                    ((ushort*)out)[(((size_t)b * NHEAD + h) * HD + d) * SEQT + tsw] = f2bf(v);
                } else {
                    int b = row >> 11, t = row & (SEQT - 1);
                    int h = col >> 6,  d = col & 63;
                    int dsw = d ^ ((t & 7) << 3);
                    ((ushort*)out)[(((size_t)b * NHEAD + h) * SEQT + t) * HD + dsw] = f2bf(v);
                }
            }
        }
    }
}

// one launch, grid (32, 8, 3): z=0 Q, z=1 K, z=2 V^T (roles swapped)
__global__ __launch_bounds__(256, 2)
void proj3_kernel(const ushort* xq, const ushort* xk, const ushort* xv,
                  const ushort* wq, const ushort* wk, const ushort* wv,
                  const float* bq, const float* bk, const float* bv,
                  ushort* oq, ushort* ok, ushort* ov)
{
    int z = blockIdx.z;
    if (z == 0)      gemm_body<0>(xq, wq, bq, oq, blockIdx.x, blockIdx.y);
    else if (z == 1) gemm_body<3>(xk, wk, bk, ok, blockIdx.x, blockIdx.y);
    else             gemm_body<2>(wv, xv, bv, ov, blockIdx.y, blockIdx.x);
}

__global__ __launch_bounds__(256, 2)
void oproj_kernel(const ushort* __restrict__ A, const ushort* __restrict__ W,
                  const float* __restrict__ bias, float* __restrict__ out)
{
    gemm_body<1>(A, W, bias, out, blockIdx.y, blockIdx.x);
}

// ---------------- flash attention (swapped-operand, 32x32 MFMA) ----------------
// grid (T/128, B*H), 256 threads = 4 waves x 32 q-rows. KBLK=64.
// 3-buffer LDS pipeline, counted vmcnt(4), raw s_barrier (T3+T4).
// All cross-lane exchanges use __shfl_xor (r2-proven). NOTE: do NOT use a
// two-operand "v_permlane32_swap %0,%1" asm with both operands fed the same
// value — the register coalescer may assign one VGPR to both, turning it
// into a self-swap (r5/r6 correctness failures).
#define KBLK 64
#define NT (SEQT / KBLK)

__global__ __launch_bounds__(256)
void attn_kernel(const ushort* __restrict__ Qg, const ushort* __restrict__ Kg,
                 const ushort* __restrict__ Vtg, ushort* __restrict__ Og)
{
    __shared__ ushort Ks[3][KBLK * HD];   // [key][d ^ 8*(key&7)]
    __shared__ ushort Vs[3][HD * KBLK];   // [d][key ^ 8*(d&7)]

    const int tid  = threadIdx.x;
    const int lane = tid & 63;
    const int wid  = tid >> 6;
    const int g    = lane >> 5;
    const int qc   = lane & 31;
    const int bh   = blockIdx.y;
    const int q0   = blockIdx.x * 128 + wid * 32;

    const ushort* Kp = Kg  + (size_t)bh * SEQT * HD;
    const ushort* Vp = Vtg + (size_t)bh * HD * SEQT;

    // Q B-fragments in registers, prescaled by log2(e)/sqrt(hd)
    const float CS = 0.18033688011112042f;
    s16x8 qf[4];
    {
        const ushort* Qp = Qg + ((size_t)bh * SEQT + q0 + qc) * HD;
#pragma unroll
        for (int kst = 0; kst < 4; kst++) {
            s16x8 raw = *reinterpret_cast<const s16x8*>(Qp + kst * 16 + g * 8);
            s16x8 sc;
#pragma unroll
            for (int j = 0; j < 8; j++) sc[j] = (short)f2bf(bf2f((ushort)raw[j]) * CS);
            qf[kst] = sc;
        }
    }

    f32x16 oa[2];
#pragma unroll
    for (int mt = 0; mt < 2; mt++)
#pragma unroll
        for (int r = 0; r < 16; r++) oa[mt][r] = 0.f;
    float mrow = -1e30f, lrow = 0.f;

#define STAGE(buf, t0)                                                               \
    do {                                                                             \
        _Pragma("unroll")                                                            \
        for (int c = 0; c < 2; c++) {                                                \
            int i = c * 256 + tid;                                                   \
            gload_lds16(Kp + (size_t)((t0) + (i >> 3)) * HD + (i & 7) * 8,           \
                        &Ks[buf][(c * 256 + wid * 64) * 8]);                         \
            gload_lds16(Vp + (size_t)(i >> 3) * SEQT + (t0) + (i & 7) * 8,           \
                        &Vs[buf][(c * 256 + wid * 64) * 8]);                         \
        }                                                                            \
    } while (0)

    // prologue: fill buffers 0,1 (8 loads/thread), wait for tile0 (oldest 4)
    STAGE(0, 0);
    STAGE(1, KBLK);
    asm volatile("s_waitcnt vmcnt(4)" ::: "memory");
    __builtin_amdgcn_s_barrier();

    for (int t = 0; t < NT; t++) {
        if (t + 2 < NT) STAGE((t + 2) % 3, (t + 2) * KBLK);
        const ushort* Kb = Ks[t % 3];
        const ushort* Vb = Vs[t % 3];

        // ---- S^T = K * Q^T : 2 m-tiles (32 keys) x 4 k-steps (16 d) ----
        f32x16 sa[2];
        __builtin_amdgcn_s_setprio(1);
#pragma unroll
        for (int mt = 0; mt < 2; mt++) {
            f32x16 a;
#pragma unroll
            for (int r = 0; r < 16; r++) a[r] = 0.f;
            const int key = mt * 32 + qc;
#pragma unroll
            for (int kst = 0; kst < 4; kst++) {
                int dsw = (kst * 16 + g * 8) ^ ((key & 7) << 3);
                s16x8 kf = *reinterpret_cast<const s16x8*>(Kb + key * HD + dsw);
                a = __builtin_amdgcn_mfma_f32_32x32x16_bf16(kf, qf[kst], a, 0, 0, 0);
            }
            sa[mt] = a;
        }
        __builtin_amdgcn_s_setprio(0);

        // ---- online softmax; lane owns q = qc, partner lane^32 has other keys ----
        float mx = sa[0][0];
#pragma unroll
        for (int r = 1; r < 16; r++) mx = fmaxf(mx, sa[0][r]);
#pragma unroll
        for (int r = 0; r < 16; r++) mx = fmaxf(mx, sa[1][r]);
        mx = fmaxf(mx, __shfl_xor(mx, 32));   // cross-half max (r2-proven)
        // T13 defer-rescale: skip alpha path unless some row grew past THR=4
        if (!__all(mx <= mrow + 4.0f)) {
            float mn = fmaxf(mrow, mx);
            float alpha = exp2f(mrow - mn);
            mrow = mn;
            lrow *= alpha;
#pragma unroll
            for (int mt = 0; mt < 2; mt++)
#pragma unroll
                for (int r = 0; r < 16; r++) oa[mt][r] *= alpha;
        }
        float rs = 0.f;
#pragma unroll
        for (int mt = 0; mt < 2; mt++)
#pragma unroll
            for (int r = 0; r < 16; r++) {
                float p = exp2f(sa[mt][r] - mrow);
                sa[mt][r] = p;
                rs += p;
            }
        rs += __shfl_xor(rs, 32);             // cross-half sum (r2-proven)
        lrow += rs;

        // ---- pack P to bf16 pairs: pk[acc][p] = keys {(2p&3)+8(p>>1)+4g, +1} ----
        uint pk[2][8];
#pragma unroll
        for (int aa = 0; aa < 2; aa++)
#pragma unroll
            for (int p = 0; p < 8; p++)
                pk[aa][p] = cvt_pk_bf16(sa[aa][2 * p], sa[aa][2 * p + 1]);

        // ---- O^T += V^T * P^T ----
#pragma unroll
        for (int kst = 0; kst < 4; kst++) {
            const int aa = kst >> 1;
            const int b4 = (kst & 1) * 4;
            // exchange complementary key-pairs with partner lane (r2-proven)
            uint s0 = g ? pk[aa][b4 + 0] : pk[aa][b4 + 2];
            uint s1 = g ? pk[aa][b4 + 1] : pk[aa][b4 + 3];
            uint r0 = __shfl_xor(s0, 32);
            uint r1 = __shfl_xor(s1, 32);
            union { uint u[4]; s16x8 v; } pf;
            pf.u[0] = g ? r0 : pk[aa][b4 + 0];
            pf.u[1] = g ? r1 : pk[aa][b4 + 1];
            pf.u[2] = g ? pk[aa][b4 + 2] : r0;
            pf.u[3] = g ? pk[aa][b4 + 3] : r1;
            __builtin_amdgcn_s_setprio(1);
#pragma unroll
            for (int mt = 0; mt < 2; mt++) {
                const int d = mt * 32 + qc;
                int ksw = (kst * 16 + g * 8) ^ ((d & 7) << 3);
                s16x8 vf = *reinterpret_cast<const s16x8*>(Vb + d * KBLK + ksw);
                oa[mt] = __builtin_amdgcn_mfma_f32_32x32x16_bf16(vf, pf.v, oa[mt], 0, 0, 0);
            }
            __builtin_amdgcn_s_setprio(0);
        }

        // counted drain: tile t+1's 4 loads done, t+2's may stay in flight
        if (t + 2 < NT)       asm volatile("s_waitcnt vmcnt(4)" ::: "memory");
        else if (t + 2 == NT) asm volatile("s_waitcnt vmcnt(0)" ::: "memory");
        __builtin_amdgcn_s_barrier();
    }

    // ---- epilogue: O^T -> per-wave LDS bounce -> coalesced bf16 stores ----
    float inv = 1.0f / lrow;
    ushort* Ob = &Ks[0][0] + wid * 2048;   // 4KB per wave, reuse K buffers
#pragma unroll
    for (int mt = 0; mt < 2; mt++)
#pragma unroll
        for (int p = 0; p < 8; p++) {
            int d = mt * 32 + ((2 * p) & 3) + 8 * (p >> 1) + 4 * g;
            uint v = cvt_pk_bf16(oa[mt][2 * p] * inv, oa[mt][2 * p + 1] * inv);
            *reinterpret_cast<uint*>(Ob + qc * HD + (d ^ ((qc & 7) << 3))) = v;
        }
    __syncthreads();
    const int b = bh >> 4, h = bh & 15;
    const int qr = lane >> 1, dh = (lane & 1) * 32;
    ushort* dst = Og + ((size_t)b * SEQT + q0 + qr) * EDIM + h * HD + dh;
    const ushort* src = Ob + qr * HD;
#pragma unroll
    for (int c = 0; c < 4; c++) {
        int d0 = (dh + c * 8) ^ ((qr & 7) << 3);
        *reinterpret_cast<s16x8*>(dst + c * 8) = *reinterpret_cast<const s16x8*>(src + d0);
    }
}

// ---------------- launch ----------------
extern "C" void kernel_launch(void* const* d_in, const int* in_sizes, int n_in,
                              void* d_out, int out_size, void* d_ws, size_t ws_size,
                              hipStream_t stream)
{
    const float* query = (const float*)d_in[0];
    const float* key   = (const float*)d_in[1];
    const float* value = (const float*)d_in[2];
    const float* Wq    = (const float*)d_in[3];
    const float* Wk    = (const float*)d_in[4];
    const float* Wv    = (const float*)d_in[5];
    const float* bq    = (const float*)d_in[6];
    const float* bk    = (const float*)d_in[7];
    const float* bv    = (const float*)d_in[8];
    const float* Wo    = (const float*)d_in[9];
    const float* bo    = (const float*)d_in[10];
    float* out = (float*)d_out;

    const size_t NX = (size_t)MTOT * EDIM;
    const size_t NW = (size_t)EDIM * EDIM;
    ushort* ws = (ushort*)d_ws;
    ushort* xq  = ws;
    ushort* xk  = xq + NX;
    ushort* xv  = xk + NX;
    ushort* wq  = xv + NX;
    ushort* wk  = wq + NW;
    ushort* wv  = wk + NW;
    ushort* wo  = wv + NW;
    ushort* qb  = wo + NW;   // (B,H,T,hd)
    ushort* kb  = qb + NX;   // (B,H,T,hd) d-swizzled
    ushort* vtb = kb + NX;   // (B,H,hd,T) key-swizzled
    ushort* ao  = vtb + NX;  // (B*T, E)

    cvt_batch<<<dim3(128, 1, 7), 256, 0, stream>>>(query, key, value, Wq, Wk, Wv, Wo,
                                                   xq, xk, xv, wq, wk, wv, wo);

    proj3_kernel<<<dim3(32, 8, 3), 256, 0, stream>>>(xq, xk, xv, wq, wk, wv,
                                                     bq, bk, bv, qb, kb, vtb);

    attn_kernel<<<dim3(SEQT / 128, MB * NHEAD), 256, 0, stream>>>(qb, kb, vtb, ao);

    oproj_kernel<<<dim3(8, 32), 256, 0, stream>>>(ao, wo, bo, out);
}